// Round 9
// baseline (43.616 us; speedup 1.0000x reference)
//
#include <hip/hip_runtime.h>
#include <stdint.h>

// Block-factorized depthwise 7x7 conv, per-(n,c,8x8-block) filters.
// feat: [N=2, C=128, H=256, W=256] f32 (NCHW)
// filters_lr: [N, C*49, 32, 32] f32 ; weight[n,hb,wb,c,t] = filt[n, c*49+t, hb, wb]
// out[n,c,h,w] = sum_t feat[n,c,h+dh-3,w+dw-3] * weight[n,h/8,w/8,c,t], t=dh*7+dw
//
// ONE WAVE PER BLOCK (64 threads), NO barrier. Each wave owns one 8-row hb
// block x 256 cols; thread = 8 rows x 4 cols. It stages its own 14 input rows
// into its own 14.8KB LDS slab via global_load_lds (16B/lane, linear dest,
// wave-uniform row base), drains with an explicit s_waitcnt vmcnt(0) (no
// s_barrier -- single wave), then computes. 11 blocks/CU resident (LDS-capped)
// with zero inter-wave sync -> CU scheduler overlaps one wave's DS/VALU with
// others' staging (r8 was overlap-bound: 4-wave lockstep barrier, ~5 waves/CU
// effective, no pipe >30%).
// Known accepted cost: lane-linear ds_read_b128 has an inherent ~23 extra
// conflict cyc/instr (each dword phase touches 8 banks) -- constant across
// r4/r8; no 16B-granular swizzle can change chunk-mod-8 uniformity.

#define LDW   264   // floats/LDS row: [0] slack, [1..3] zero pad, [4..259] data, [260..262] pad, [263] slack
#define NROWS 14    // 8 output rows + 6 halo

typedef const uint32_t __attribute__((address_space(1))) guint;
typedef uint32_t __attribute__((address_space(3))) luint;

__global__ __launch_bounds__(64, 2)
void block_fac_kernel(const float* __restrict__ feat,
                      const float* __restrict__ filt,
                      float* __restrict__ out) {
    __shared__ float s_in[NROWS * LDW];   // 14784 B -> 11 blocks/CU

    const int bid = blockIdx.x;           // n*128*32 + c*32 + hb
    const int hb  = bid & 31;
    const int c   = (bid >> 5) & 127;
    const int n   = bid >> 12;
    const int lane = threadIdx.x;         // 0..63

    const int c0 = lane << 2;             // output col base (0..252)
    const int wb = lane >> 1;             // weight block col (0..31)

    // ---- weights: global -> VGPR, one coalesced 128B line per tap;
    //      issued first, drains concurrently with the staging queue.
    const float* wgbase = filt + (size_t)((n * 128 + c) * 49) * 1024 + hb * 32 + wb;
    float wt[49];
    #pragma unroll
    for (int t = 0; t < 49; ++t) wt[t] = wgbase[(size_t)t * 1024];

    const int H0 = hb * 8;                // first output row
    const int h0 = H0 - 3;                // first staged input row

    // ---- zero the 3-col pads (float idx 1..3 and 260..262): 14*6 = 84 words
    for (int idx = lane; idx < NROWS * 6; idx += 64) {
        int r = idx / 6, j = idx - r * 6;
        int p = (j < 3) ? (1 + j) : (257 + j);
        s_in[r * LDW + p] = 0.f;
    }

    // ---- stage input rows h0..h0+13 via global_load_lds (16B/lane, linear dest)
    const float* fbase = feat + (size_t)(n * 128 + c) * (256 * 256);
    #pragma unroll
    for (int r = 0; r < NROWS; ++r) {     // row uniform; lane supplies 16B chunk
        int gr = h0 + r;
        float* lp = &s_in[r * LDW + 4];   // wave-uniform base; HW adds lane*16
        if (gr >= 0 && gr < 256) {        // uniform branch
            const float* gp = fbase + (size_t)gr * 256 + (lane << 2);
            __builtin_amdgcn_global_load_lds((guint*)gp, (luint*)lp, 16, 0, 0);
        } else {
            *(float4*)(&s_in[r * LDW + 4 + (lane << 2)]) =
                make_float4(0.f, 0.f, 0.f, 0.f);
        }
    }
    // single wave: no s_barrier needed; just drain the global->LDS queue.
    asm volatile("s_waitcnt vmcnt(0)" ::: "memory");

    // ---- compute: thread -> rows H0..H0+7, cols c0..c0+3
    float acc[8][4] = {};

    #pragma unroll
    for (int jj = 0; jj < NROWS; ++jj) {  // staged row jj; out row a uses dh=jj-a
        const float* rp = &s_in[jj * LDW + c0];   // byte = jj*1056 + lane*16, 16B aligned
        float4 a0 = *(const float4*)(rp);
        float4 a1 = *(const float4*)(rp + 4);
        float4 a2 = *(const float4*)(rp + 8);
        float win[12] = {a0.x, a0.y, a0.z, a0.w,
                         a1.x, a1.y, a1.z, a1.w,
                         a2.x, a2.y, a2.z, a2.w};
        #pragma unroll
        for (int a = 0; a < 8; ++a) {
            int dh = jj - a;
            if (dh >= 0 && dh <= 6) {
                #pragma unroll
                for (int dw = 0; dw < 7; ++dw) {
                    float wv = wt[dh * 7 + dw];
                    #pragma unroll
                    for (int i = 0; i < 4; ++i)
                        acc[a][i] += win[i + dw + 1] * wv;   // col c0+i+dw-3
                }
            }
        }
    }

    float* obase = out + (size_t)((n * 128 + c) * 256 + H0) * 256 + c0;
    #pragma unroll
    for (int a = 0; a < 8; ++a)
        *(float4*)(obase + (size_t)(a * 256)) =
            make_float4(acc[a][0], acc[a][1], acc[a][2], acc[a][3]);
}

extern "C" void kernel_launch(void* const* d_in, const int* in_sizes, int n_in,
                              void* d_out, int out_size, void* d_ws, size_t ws_size,
                              hipStream_t stream) {
    const float* feat = (const float*)d_in[0];
    const float* filt = (const float*)d_in[1];
    float* out = (float*)d_out;
    dim3 grid(2 * 128 * 32);
    dim3 block(64);
    hipLaunchKernelGGL(block_fac_kernel, grid, block, 0, stream, feat, filt, out);
}

// Round 10
// 41.240 us; speedup vs baseline: 1.0576x; 1.0576x over previous
//
#include <hip/hip_runtime.h>

// Block-factorized depthwise 7x7 conv, per-(n,c,8x8-block) filters.
// feat: [N=2, C=128, H=256, W=256] f32 (NCHW)
// filters_lr: [N, C*49, 32, 32] f32 ; weight[n,hb,wb,c,t] = filt[n, c*49+t, hb, wb]
// out[n,c,h,w] = sum_t feat[n,c,h+dh-3,w+dw-3] * weight[n,h/8,w/8,c,t], t=dh*7+dw
//
// SHUFFLE-HALO, zero LDS, zero barriers, zero manual waitcnt.
// One wave (64 thr) per 8-row hb block; thread = 8 rows x 4 cols.
//  - 14 row loads (own float4, address-CLAMPED so they are unconditional and
//    hoist to the top) + 49 weight loads: all plain loads -> the compiler's
//    waitcnt pass inserts per-use COUNTED vmcnt (r4/r8/r9 all drained
//    vmcnt(0) before the first FMA; that wait-all was ~28k of the ~32k cyc
//    wave lifetime).
//  - Horizontal halo via ds_bpermute from neighbor lanes (crossbar,
//    conflict-free) instead of LDS tile reads (16B-lane-stride ds_read_b128
//    is inherently 8-way bank-conflicted: constant 23 extra cyc/instr across
//    r2-r9).
//  - Row/lane edges masked at USE time (cndmask), so no branch traps loads.

__global__ __launch_bounds__(64, 1)
void block_fac_kernel(const float* __restrict__ feat,
                      const float* __restrict__ filt,
                      float* __restrict__ out) {
    const int bid = blockIdx.x;           // n*128*32 + c*32 + hb
    const int hb  = bid & 31;
    const int c   = (bid >> 5) & 127;
    const int n   = bid >> 12;
    const int lane = threadIdx.x;         // 0..63

    const int c0 = lane << 2;             // output col base (0..252)
    const int wb = lane >> 1;             // weight block col (0..31)
    const int H0 = hb * 8;                // first output row

    const float* fbase  = feat + (size_t)(n * 128 + c) * (256 * 256);
    const float* wgbase = filt + (size_t)((n * 128 + c) * 49) * 1024 + hb * 32 + wb;

    // ---- 14 input rows: own float4 only, clamped address -> unconditional.
    float4 row[14];
    #pragma unroll
    for (int r = 0; r < 14; ++r) {
        int gr  = H0 - 3 + r;
        int grc = gr < 0 ? 0 : (gr > 255 ? 255 : gr);
        row[r] = *(const float4*)(fbase + (size_t)grc * 256 + c0);
    }

    // ---- 49 weights (one coalesced 128B line per tap; lane pairs share).
    float wt[49];
    #pragma unroll
    for (int t = 0; t < 49; ++t) wt[t] = wgbase[(size_t)t * 1024];

    const int addrL = ((lane - 1) & 63) << 2;   // bpermute byte index: pull from lane-1
    const int addrR = ((lane + 1) & 63) << 2;   // pull from lane+1
    const bool l0  = (lane == 0);
    const bool l63 = (lane == 63);

    float acc[8][4] = {};

    #pragma unroll
    for (int jj = 0; jj < 14; ++jj) {     // input row H0-3+jj ; out row a uses dh=jj-a
        const int gr = H0 - 3 + jj;       // wave-uniform validity
        float4 f = row[jj];
        if (gr < 0 || gr > 255) f = make_float4(0.f, 0.f, 0.f, 0.f);

        // halo from neighbor lanes (conflict-free crossbar)
        float L1 = __int_as_float(__builtin_amdgcn_ds_bpermute(addrL, __float_as_int(f.y)));
        float L2 = __int_as_float(__builtin_amdgcn_ds_bpermute(addrL, __float_as_int(f.z)));
        float L3 = __int_as_float(__builtin_amdgcn_ds_bpermute(addrL, __float_as_int(f.w)));
        float R0 = __int_as_float(__builtin_amdgcn_ds_bpermute(addrR, __float_as_int(f.x)));
        float R1 = __int_as_float(__builtin_amdgcn_ds_bpermute(addrR, __float_as_int(f.y)));
        float R2 = __int_as_float(__builtin_amdgcn_ds_bpermute(addrR, __float_as_int(f.z)));
        if (l0)  { L1 = 0.f; L2 = 0.f; L3 = 0.f; }   // cols -3..-1
        if (l63) { R0 = 0.f; R1 = 0.f; R2 = 0.f; }   // cols 256..258

        // win[k] = feat col c0 + k - 4 (k=1..10 used)
        float win[12] = {0.f, L1, L2, L3,
                         f.x, f.y, f.z, f.w,
                         R0, R1, R2, 0.f};
        #pragma unroll
        for (int a = 0; a < 8; ++a) {
            int dh = jj - a;
            if (dh >= 0 && dh <= 6) {
                #pragma unroll
                for (int dw = 0; dw < 7; ++dw) {
                    float wv = wt[dh * 7 + dw];
                    #pragma unroll
                    for (int i = 0; i < 4; ++i)
                        acc[a][i] += win[i + dw + 1] * wv;   // col c0+i+dw-3
                }
            }
        }
    }

    float* obase = out + (size_t)((n * 128 + c) * 256 + H0) * 256 + c0;
    #pragma unroll
    for (int a = 0; a < 8; ++a)
        *(float4*)(obase + (size_t)(a * 256)) =
            make_float4(acc[a][0], acc[a][1], acc[a][2], acc[a][3]);
}

extern "C" void kernel_launch(void* const* d_in, const int* in_sizes, int n_in,
                              void* d_out, int out_size, void* d_ws, size_t ws_size,
                              hipStream_t stream) {
    const float* feat = (const float*)d_in[0];
    const float* filt = (const float*)d_in[1];
    float* out = (float*)d_out;
    dim3 grid(2 * 128 * 32);
    dim3 block(64);
    hipLaunchKernelGGL(block_fac_kernel, grid, block, 0, stream, feat, filt, out);
}

// Round 11
// 40.702 us; speedup vs baseline: 1.0716x; 1.0132x over previous
//
#include <hip/hip_runtime.h>

// Block-factorized depthwise 7x7 conv, per-(n,c,8x8-block) filters.
// feat: [N=2, C=128, H=256, W=256] f32 (NCHW)
// filters_lr: [N, C*49, 32, 32] f32 ; weight[n,hb,wb,c,t] = filt[n, c*49+t, hb, wb]
// out[n,c,h,w] = sum_t feat[n,c,h+dh-3,w+dw-3] * weight[n,h/8,w/8,c,t], t=dh*7+dw
//
// r10 shuffle-halo wave (zero LDS / barriers / manual waitcnt), but FOUR
// independent waves packed per 256-thread workgroup. r9/r10 both pinned at
// ~5.5 resident waves/CU regardless of LDS/VGPR limits -> residency looks
// WG-slot-bound, not resource-bound; 1-wave blocks waste 3/4 of each slot.
// Each wave here is byte-identical work to r10 (wave-id = global wave index);
// no inter-wave interaction, so no barrier needed.

__global__ __launch_bounds__(256, 1)
void block_fac_kernel(const float* __restrict__ feat,
                      const float* __restrict__ filt,
                      float* __restrict__ out) {
    const int wid = (blockIdx.x << 2) | (threadIdx.x >> 6);   // global wave id
    const int hb  = wid & 31;
    const int c   = (wid >> 5) & 127;
    const int n   = wid >> 12;
    const int lane = threadIdx.x & 63;

    const int c0 = lane << 2;             // output col base (0..252)
    const int wb = lane >> 1;             // weight block col (0..31)
    const int H0 = hb * 8;                // first output row

    const float* fbase  = feat + (size_t)(n * 128 + c) * (256 * 256);
    const float* wgbase = filt + (size_t)((n * 128 + c) * 49) * 1024 + hb * 32 + wb;

    // ---- 14 input rows: own float4 only, clamped address -> unconditional.
    float4 row[14];
    #pragma unroll
    for (int r = 0; r < 14; ++r) {
        int gr  = H0 - 3 + r;
        int grc = gr < 0 ? 0 : (gr > 255 ? 255 : gr);
        row[r] = *(const float4*)(fbase + (size_t)grc * 256 + c0);
    }

    // ---- 49 weights (one coalesced 128B line per tap; lane pairs share).
    float wt[49];
    #pragma unroll
    for (int t = 0; t < 49; ++t) wt[t] = wgbase[(size_t)t * 1024];

    const int addrL = ((lane - 1) & 63) << 2;   // bpermute: pull from lane-1
    const int addrR = ((lane + 1) & 63) << 2;   // pull from lane+1
    const bool l0  = (lane == 0);
    const bool l63 = (lane == 63);

    float acc[8][4] = {};

    #pragma unroll
    for (int jj = 0; jj < 14; ++jj) {     // input row H0-3+jj ; out row a uses dh=jj-a
        const int gr = H0 - 3 + jj;       // wave-uniform validity
        float4 f = row[jj];
        if (gr < 0 || gr > 255) f = make_float4(0.f, 0.f, 0.f, 0.f);

        // halo from neighbor lanes (conflict-free crossbar)
        float L1 = __int_as_float(__builtin_amdgcn_ds_bpermute(addrL, __float_as_int(f.y)));
        float L2 = __int_as_float(__builtin_amdgcn_ds_bpermute(addrL, __float_as_int(f.z)));
        float L3 = __int_as_float(__builtin_amdgcn_ds_bpermute(addrL, __float_as_int(f.w)));
        float R0 = __int_as_float(__builtin_amdgcn_ds_bpermute(addrR, __float_as_int(f.x)));
        float R1 = __int_as_float(__builtin_amdgcn_ds_bpermute(addrR, __float_as_int(f.y)));
        float R2 = __int_as_float(__builtin_amdgcn_ds_bpermute(addrR, __float_as_int(f.z)));
        if (l0)  { L1 = 0.f; L2 = 0.f; L3 = 0.f; }   // cols -3..-1
        if (l63) { R0 = 0.f; R1 = 0.f; R2 = 0.f; }   // cols 256..258

        // win[k] = feat col c0 + k - 4 (k=1..10 used)
        float win[12] = {0.f, L1, L2, L3,
                         f.x, f.y, f.z, f.w,
                         R0, R1, R2, 0.f};
        #pragma unroll
        for (int a = 0; a < 8; ++a) {
            int dh = jj - a;
            if (dh >= 0 && dh <= 6) {
                #pragma unroll
                for (int dw = 0; dw < 7; ++dw) {
                    float wv = wt[dh * 7 + dw];
                    #pragma unroll
                    for (int i = 0; i < 4; ++i)
                        acc[a][i] += win[i + dw + 1] * wv;   // col c0+i+dw-3
                }
            }
        }
    }

    float* obase = out + (size_t)((n * 128 + c) * 256 + H0) * 256 + c0;
    #pragma unroll
    for (int a = 0; a < 8; ++a)
        *(float4*)(obase + (size_t)(a * 256)) =
            make_float4(acc[a][0], acc[a][1], acc[a][2], acc[a][3]);
}

extern "C" void kernel_launch(void* const* d_in, const int* in_sizes, int n_in,
                              void* d_out, int out_size, void* d_ws, size_t ws_size,
                              hipStream_t stream) {
    const float* feat = (const float*)d_in[0];
    const float* filt = (const float*)d_in[1];
    float* out = (float*)d_out;
    dim3 grid(2 * 128 * 32 / 4);          // 2048 blocks x 4 waves
    dim3 block(256);
    hipLaunchKernelGGL(block_fac_kernel, grid, block, 0, stream, feat, filt, out);
}

// Round 12
// 40.598 us; speedup vs baseline: 1.0743x; 1.0026x over previous
//
#include <hip/hip_runtime.h>
#include <stdint.h>

// Block-factorized depthwise 7x7 conv, per-(n,c,8x8-block) filters.
// feat: [N=2, C=128, H=256, W=256] f32 (NCHW)
// filters_lr: [N, C*49, 32, 32] f32 ; weight[n,hb,wb,c,t] = filt[n, c*49+t, hb, wb]
// out[n,c,h,w] = sum_t feat[n,c,h+dh-3,w+dw-3] * weight[n,h/8,w/8,c,t], t=dh*7+dw
//
// r10 shuffle-halo compute (bpermute halo, clamped row loads, no barriers),
// but the WEIGHT GATHER is restructured to be zero-VGPR and single-epoch:
//  - 7 global_load_lds instructions stage the wave's 6272B weight block
//    (49 taps x 128B, scattered at 4KB stride in filt) into a per-wave LDS
//    slab. Global source addrs are per-lane (scatter OK); LDS dest is the
//    HW-required linear base+lane*16.
//  - ONE explicit s_waitcnt vmcnt(0) drains weights + 14 feature-row loads
//    together (r9-r11 burned ~14k cyc/wave in several serialized ~900cyc
//    epochs because 49 weight loads needed 49 result VGPRs and couldn't all
//    be in flight).
//  - Weights then hoist LDS->reg as 49 ds_read_b32: addr = slab + t*128B +
//    wb*4B -> bank == wb, lane pairs broadcast => conflict-free, ~120cyc.
// VGPR must stay <=128 (waves/CU halves at 129): persistent state unchanged
// vs r10's 116 (49 wt + 32 acc + rows), staging uses no result regs.

#define SLABF 1568   // floats per wave weight slab (49 taps * 32 wb)

typedef const uint32_t __attribute__((address_space(1))) guint;
typedef uint32_t __attribute__((address_space(3))) luint;

__global__ __launch_bounds__(256, 1)
void block_fac_kernel(const float* __restrict__ feat,
                      const float* __restrict__ filt,
                      float* __restrict__ out) {
    __shared__ float s_w[4 * SLABF];      // 25088 B, one slab per wave

    const int wave = threadIdx.x >> 6;
    const int lane = threadIdx.x & 63;
    const int wid  = (blockIdx.x << 2) | wave;   // global wave id
    const int hb   = wid & 31;
    const int c    = (wid >> 5) & 127;
    const int n    = wid >> 12;

    const int c0 = lane << 2;             // output col base (0..252)
    const int wb = lane >> 1;             // weight block col (0..31)
    const int H0 = hb * 8;                // first output row

    const float* fbase = feat + (size_t)(n * 128 + c) * (256 * 256);
    const float* wtap  = filt + (size_t)((n * 128 + c) * 49) * 1024 + hb * 32;
    float* slab = s_w + wave * SLABF;

    // ---- stage the 6272B weight block into LDS: 7 fire-and-forget gathers.
    // flat 16B-chunk f = i*64+lane ; tap t = f>>3 ; chunk = f&7.
    #pragma unroll
    for (int i = 0; i < 7; ++i) {
        if (i < 6 || lane < 8) {          // tail instr: only taps 48 (8 chunks)
            int f = (i << 6) | lane;
            const float* gp = wtap + (size_t)(f >> 3) * 1024 + (f & 7) * 4;
            float* lp = slab + i * 256;   // wave-uniform base; HW adds lane*16
            __builtin_amdgcn_global_load_lds((guint*)gp, (luint*)lp, 16, 0, 0);
        }
    }

    // ---- 14 input rows: own float4, clamped address -> unconditional.
    float4 row[14];
    #pragma unroll
    for (int r = 0; r < 14; ++r) {
        int gr  = H0 - 3 + r;
        int grc = gr < 0 ? 0 : (gr > 255 ? 255 : gr);
        row[r] = *(const float4*)(fbase + (size_t)grc * 256 + c0);
    }

    // single latency epoch: weights (LDS) + rows (regs) drain together.
    asm volatile("s_waitcnt vmcnt(0)" ::: "memory");
    __builtin_amdgcn_sched_barrier(0);

    // ---- weights LDS -> reg: 49 conflict-free b32 (bank = wb, pair-broadcast)
    const float* ws = slab + wb;
    float wt[49];
    #pragma unroll
    for (int t = 0; t < 49; ++t) wt[t] = ws[t * 32];

    const int addrL = ((lane - 1) & 63) << 2;   // bpermute: pull from lane-1
    const int addrR = ((lane + 1) & 63) << 2;   // pull from lane+1
    const bool l0  = (lane == 0);
    const bool l63 = (lane == 63);

    float acc[8][4] = {};

    #pragma unroll
    for (int jj = 0; jj < 14; ++jj) {     // input row H0-3+jj ; out row a uses dh=jj-a
        const int gr = H0 - 3 + jj;       // wave-uniform validity
        float4 f = row[jj];
        if (gr < 0 || gr > 255) f = make_float4(0.f, 0.f, 0.f, 0.f);

        float L1 = __int_as_float(__builtin_amdgcn_ds_bpermute(addrL, __float_as_int(f.y)));
        float L2 = __int_as_float(__builtin_amdgcn_ds_bpermute(addrL, __float_as_int(f.z)));
        float L3 = __int_as_float(__builtin_amdgcn_ds_bpermute(addrL, __float_as_int(f.w)));
        float R0 = __int_as_float(__builtin_amdgcn_ds_bpermute(addrR, __float_as_int(f.x)));
        float R1 = __int_as_float(__builtin_amdgcn_ds_bpermute(addrR, __float_as_int(f.y)));
        float R2 = __int_as_float(__builtin_amdgcn_ds_bpermute(addrR, __float_as_int(f.z)));
        if (l0)  { L1 = 0.f; L2 = 0.f; L3 = 0.f; }   // cols -3..-1
        if (l63) { R0 = 0.f; R1 = 0.f; R2 = 0.f; }   // cols 256..258

        // win[k] = feat col c0 + k - 4 (k=1..10 used)
        float win[12] = {0.f, L1, L2, L3,
                         f.x, f.y, f.z, f.w,
                         R0, R1, R2, 0.f};
        #pragma unroll
        for (int a = 0; a < 8; ++a) {
            int dh = jj - a;
            if (dh >= 0 && dh <= 6) {
                #pragma unroll
                for (int dw = 0; dw < 7; ++dw) {
                    float wv = wt[dh * 7 + dw];
                    #pragma unroll
                    for (int i = 0; i < 4; ++i)
                        acc[a][i] += win[i + dw + 1] * wv;   // col c0+i+dw-3
                }
            }
        }
    }

    float* obase = out + (size_t)((n * 128 + c) * 256 + H0) * 256 + c0;
    #pragma unroll
    for (int a = 0; a < 8; ++a)
        *(float4*)(obase + (size_t)(a * 256)) =
            make_float4(acc[a][0], acc[a][1], acc[a][2], acc[a][3]);
}

extern "C" void kernel_launch(void* const* d_in, const int* in_sizes, int n_in,
                              void* d_out, int out_size, void* d_ws, size_t ws_size,
                              hipStream_t stream) {
    const float* feat = (const float*)d_in[0];
    const float* filt = (const float*)d_in[1];
    float* out = (float*)d_out;
    dim3 grid(2 * 128 * 32 / 4);          // 2048 blocks x 4 waves
    dim3 block(256);
    hipLaunchKernelGGL(block_fac_kernel, grid, block, 0, stream, feat, filt, out);
}